// Round 5
// baseline (61.184 us; speedup 1.0000x reference)
//
#include <hip/hip_runtime.h>
#include <hip/hip_bf16.h>
#include <math.h>

#define NROW  256
#define DIM   65536
#define BKF   32         // k-floats per pipeline step (128 B/row/step)
#define DEPTH 4          // circular LDS buffers
#define NSTEP 8          // steps per block: 256 blocks * 8 * 32 = 65536 = DIM

typedef __attribute__((ext_vector_type(8))) short short8;
typedef __attribute__((ext_vector_type(4))) float f32x4;
typedef unsigned int       u32t;
typedef unsigned long long u64t;

__device__ __forceinline__ float bf2f(ushort h) {
    u32t u = ((u32t)h) << 16;
    return __builtin_bit_cast(float, u);
}
// packed fp32x2 -> bf16x2 (v_cvt_pk_bf16_f32, RNE)
__device__ __forceinline__ u32t pk2(float lo, float hi) {
    __hip_bfloat162 h = __float22bfloat162_rn(make_float2(lo, hi));
    u32t r; __builtin_memcpy(&r, &h, 4); return r;
}
// 8 consecutive-k fp32 (two f32x4, k-order) -> bf16x8 MFMA fragment
__device__ __forceinline__ short8 mkfrag(f32x4 lo, f32x4 hi) {
    union { uint4 u; short8 s; } f;
    f.u.x = pk2(lo[0], lo[1]); f.u.y = pk2(lo[2], lo[3]);
    f.u.z = pk2(hi[0], hi[1]); f.u.w = pk2(hi[2], hi[3]);
    return f.s;
}

// native-layout position of G[i][j] (matches gemm epilogue store order)
__device__ __forceinline__ int gpos(int i, int j) {
    const int wid  = ((i >> 7) << 2) | (j >> 6);
    const int lane = (((i >> 2) & 3) << 4) | (j & 15);
    const int m = (i >> 4) & 7, n = (j >> 4) & 3, jr = i & 3;
    return ((wid << 6) | lane) * 128 + (((m << 2) | n) << 2) + jr;
}

// ---------------------------------------------------------------------------
// Split-K MFMA GEMM, T3+T4 pipeline: block s owns K-range [s*256, s*256+256).
// E staged fp32 via global_load_lds into DEPTH=4 circular LDS buffers
// (linear LDS dest; bank-swizzle via pre-swizzled per-lane SOURCE address,
// granule g^=(row&7) — same 128B lines fetched). Counted vmcnt(8) keeps
// 2-3 steps (64-96 KiB/CU) in flight across raw s_barriers — no drain.
// bf16 conversion fused into fragment reads. Partials bf16, native layout.
// ---------------------------------------------------------------------------
__global__ __launch_bounds__(512, 2) void gemm_mfma(const float* __restrict__ E,
                                                    ushort* __restrict__ part) {
    const int s    = blockIdx.x;
    const int tid  = threadIdx.x;
    const int lane = tid & 63;
    const int wid  = tid >> 6;
    const int wr   = wid >> 2;          // 0..1 -> 128-row band
    const int wc   = wid & 3;           // 0..3 -> 64-col band
    const int r15  = lane & 15;
    const int kgi  = lane >> 4;         // 0..3 -> 8-k slice within BKF

    __shared__ float Es[DEPTH][NROW][BKF];   // 128 KiB

    f32x4 acc[8][4];
    #pragma unroll
    for (int m = 0; m < 8; ++m)
        #pragma unroll
        for (int n = 0; n < 4; ++n) acc[m][n] = (f32x4){0.f, 0.f, 0.f, 0.f};

    // staging: instr (wid,jj) covers rows rg*8..rg*8+7 (rg=wid*4+jj),
    // LDS dest = uniform base + lane*16 (linear). Source granule swizzled.
    const int srow8 = lane >> 3;        // row within 8-row group
    const int gdst  = lane & 7;         // 16B granule slot within row
    const size_t kbase = (size_t)s * (NSTEP * BKF);

    auto STAGE = [&](int t, int b) {
        #pragma unroll
        for (int jj = 0; jj < 4; ++jj) {
            const int rg  = wid * 4 + jj;
            const int row = rg * 8 + srow8;
            const float* src = E + (size_t)row * DIM + kbase + (size_t)t * BKF
                                 + ((gdst ^ (row & 7)) << 2);
            __builtin_amdgcn_global_load_lds(
                (const __attribute__((address_space(1))) void*)src,
                (__attribute__((address_space(3))) void*)&Es[b][rg * 8][0],
                16, 0, 0);
        }
    };

    #pragma unroll
    for (int d = 0; d < 3; ++d) STAGE(d, d);    // prologue: 3 steps in flight

    for (int t = 0; t < NSTEP; ++t) {
        const int b   = t & (DEPTH - 1);
        const int rem = NSTEP - 1 - t;
        if (rem >= 2)      asm volatile("s_waitcnt vmcnt(8)" ::: "memory");
        else if (rem == 1) asm volatile("s_waitcnt vmcnt(4)" ::: "memory");
        else               asm volatile("s_waitcnt vmcnt(0)" ::: "memory");
        __builtin_amdgcn_s_barrier();           // step-t tile staged, all waves
        __builtin_amdgcn_sched_barrier(0);
        if (t + 3 < NSTEP) STAGE(t + 3, (t + 3) & (DEPTH - 1));

        short8 af[8], bfr[4];
        #pragma unroll
        for (int m = 0; m < 8; ++m) {
            const int row = wr * 128 + m * 16 + r15;
            const int x   = row & 7;
            const f32x4 lo = *(const f32x4*)&Es[b][row][((2 * kgi)     ^ x) << 2];
            const f32x4 hi = *(const f32x4*)&Es[b][row][((2 * kgi + 1) ^ x) << 2];
            af[m] = mkfrag(lo, hi);
        }
        #pragma unroll
        for (int n = 0; n < 4; ++n) {
            const int row = wc * 64 + n * 16 + r15;
            const int x   = row & 7;
            const f32x4 lo = *(const f32x4*)&Es[b][row][((2 * kgi)     ^ x) << 2];
            const f32x4 hi = *(const f32x4*)&Es[b][row][((2 * kgi + 1) ^ x) << 2];
            bfr[n] = mkfrag(lo, hi);
        }
        #pragma unroll
        for (int m = 0; m < 8; ++m)
            #pragma unroll
            for (int n = 0; n < 4; ++n)
                acc[m][n] = __builtin_amdgcn_mfma_f32_16x16x32_bf16(
                    af[m], bfr[n], acc[m][n], 0, 0, 0);
    }

    // epilogue: 128 accs -> bf16, contiguous per-thread (coalesced 16B stores)
    ushort* pp = part + (size_t)s * (NROW * NROW) + (size_t)tid * 128;
    #pragma unroll
    for (int m = 0; m < 8; ++m)
        #pragma unroll
        for (int n = 0; n < 4; n += 2) {
            uint4 q;
            q.x = pk2(acc[m][n][0],     acc[m][n][1]);
            q.y = pk2(acc[m][n][2],     acc[m][n][3]);
            q.z = pk2(acc[m][n + 1][0], acc[m][n + 1][1]);
            q.w = pk2(acc[m][n + 1][2], acc[m][n + 1][3]);
            *(uint4*)(pp + ((m << 2) | n) * 4) = q;
        }
}

// Fixed-order sum of P=256 bf16 partials -> Gn (fp32, native layout). Also
// zeroes the fixed-point accumulator for the fused row_loss (stream-ordered).
__global__ __launch_bounds__(256) void reduce_k(const ushort* __restrict__ part,
                                                float* __restrict__ Gn,
                                                u64t* __restrict__ acc,
                                                u32t* __restrict__ cnt, int P) {
    if (blockIdx.x == 0 && threadIdx.x == 0) { *acc = 0ull; *cnt = 0u; }

    const int b = blockIdx.x, t = threadIdx.x;
    const int l = t & 63, sg = t >> 6;
    const int n0 = b * 256 + l * 4;

    float a0 = 0.f, a1 = 0.f, a2 = 0.f, a3 = 0.f;
    for (int s = sg; s < P; s += 4) {
        const ushort4 u = *(const ushort4*)&part[(size_t)s * (NROW * NROW) + n0];
        a0 += bf2f(u.x); a1 += bf2f(u.y); a2 += bf2f(u.z); a3 += bf2f(u.w);
    }
    __shared__ float sh[4][256];
    sh[sg][l * 4 + 0] = a0; sh[sg][l * 4 + 1] = a1;
    sh[sg][l * 4 + 2] = a2; sh[sg][l * 4 + 3] = a3;
    __syncthreads();
    Gn[b * 256 + t] = (sh[0][t] + sh[1][t]) + (sh[2][t] + sh[3][t]);
}

// ---------------------------------------------------------------------------
// Fused per-row softmax loss + deterministic final sum (fixed-point atomic,
// order-independent). PSD term provably 0 (AM-GM; clip at 0), omitted.
// ---------------------------------------------------------------------------
__global__ __launch_bounds__(256) void row_loss_k(const float* __restrict__ Gn,
                                                  const int* __restrict__ labels,
                                                  u64t* __restrict__ acc,
                                                  u32t* __restrict__ cnt,
                                                  float* __restrict__ out) {
    const int i = blockIdx.x;
    const int j = threadIdx.x;

    const float Gii = Gn[gpos(i, i)];
    const float Gjj = Gn[gpos(j, j)];
    const float Gij = Gn[gpos(i, j)];
    const float d2 = fmaxf(Gii + Gjj - 2.0f * Gij, 0.0f);
    const bool diag = (j == i);
    const float sc = diag ? -3.0e38f : -sqrtf(d2);

    __shared__ float red0[4], red1[4];

    float m = sc;
    #pragma unroll
    for (int off = 32; off; off >>= 1) m = fmaxf(m, __shfl_xor(m, off, 64));
    const int w = j >> 6;
    if ((j & 63) == 0) red0[w] = m;
    __syncthreads();
    m = fmaxf(fmaxf(red0[0], red0[1]), fmaxf(red0[2], red0[3]));

    const float p  = diag ? 0.0f : expf(sc - m);
    const float nm = (labels[j] == labels[i]) ? p : 0.0f;

    float zs = p, ns = nm;
    #pragma unroll
    for (int off = 32; off; off >>= 1) {
        zs += __shfl_xor(zs, off, 64);
        ns += __shfl_xor(ns, off, 64);
    }
    __syncthreads();
    if ((j & 63) == 0) { red0[w] = zs; red1[w] = ns; }
    __syncthreads();
    if (j == 0) {
        const float Z = red0[0] + red0[1] + red0[2] + red0[3];
        const float N = red1[0] + red1[1] + red1[2] + red1[3];
        const float rl = logf(Z) - logf(N);          // >= 0 (N subset of Z)
        const long long q = llrintf(rl * 1048576.0f);
        atomicAdd(acc, (u64t)q);
        __threadfence();
        const u32t c = atomicAdd(cnt, 1u);
        if (c == NROW - 1) {
            __threadfence();
            const u64t tot = atomicAdd(acc, 0ull);
            out[0] = (float)((double)(long long)tot * (1.0 / 1048576.0) * 0.005);
        }
    }
}

extern "C" void kernel_launch(void* const* d_in, const int* in_sizes, int n_in,
                              void* d_out, int out_size, void* d_ws, size_t ws_size,
                              hipStream_t stream) {
    const float* E      = (const float*)d_in[0];
    const int*   labels = (const int*)d_in[1];
    float*       out    = (float*)d_out;

    const int P = 256;   // ws is ~268 MB (observed); need ~34 MB

    ushort* part = (ushort*)d_ws;
    float*  Gn   = (float*)((char*)d_ws + (size_t)P * NROW * NROW * sizeof(ushort));
    u64t*   acc  = (u64t*)(Gn + NROW * NROW);
    u32t*   cnt  = (u32t*)(acc + 1);

    gemm_mfma <<<P, 512, 0, stream>>>(E, part);
    reduce_k  <<<NROW, 256, 0, stream>>>(part, Gn, acc, cnt, P);
    row_loss_k<<<NROW, 256, 0, stream>>>(Gn, labels, acc, cnt, out);
}

// Round 6
// 58.415 us; speedup vs baseline: 1.0474x; 1.0474x over previous
//
#include <hip/hip_runtime.h>
#include <hip/hip_bf16.h>
#include <math.h>

#define NROW 256
#define DIM  65536
#define KB   256            // k-floats per block (P = 256 split-K blocks)
#define LR   264            // LDS row stride in bf16 elems (256 + 8 pad)
#define PSP  65600          // partial-buffer stride in ushorts (65536 + 64 pad)

typedef __attribute__((ext_vector_type(8))) short short8;
typedef __attribute__((ext_vector_type(4))) float f32x4;
typedef unsigned int       u32t;
typedef unsigned long long u64t;

__device__ __forceinline__ float bf2f(ushort h) {
    u32t u = ((u32t)h) << 16;
    return __builtin_bit_cast(float, u);
}
// packed fp32x2 -> bf16x2 (v_cvt_pk_bf16_f32, RNE)
__device__ __forceinline__ u32t pk2(float lo, float hi) {
    __hip_bfloat162 h = __float22bfloat162_rn(make_float2(lo, hi));
    u32t r; __builtin_memcpy(&r, &h, 4); return r;
}

// native-layout position of G[i][j] (matches gemm epilogue store order)
__device__ __forceinline__ int gpos(int i, int j) {
    const int wid  = ((i >> 7) << 2) | (j >> 6);
    const int lane = (((i >> 2) & 3) << 4) | (j & 15);
    const int m = (i >> 4) & 7, n = (j >> 4) & 3, jr = i & 3;
    return ((wid << 6) | lane) * 128 + (((m << 2) | n) << 2) + jr;
}

// ---------------------------------------------------------------------------
// Fused split-K MFMA GEMM, single-barrier structure.
// Block s owns K-range [s*256, (s+1)*256) floats.
// Phase A: stream the block's full 256-row x 256-k fp32 tile (256 KB) through
//   registers -> cvt_pk -> bf16 LDS (132 KB, padded row stride 264 elems so
//   banks rotate by 4 per row: balanced ds_write_b64 and ds_read_b128, no
//   swizzle). 1 KB contiguous per row per block, deep ILP, compiler waitcnts.
// ONE __syncthreads.
// Phase B: 8 MFMA k-steps (K=32 each, k-ascending) pure LDS -> AGPR, no
//   global traffic, no barriers. Each wave owns a 128x64 output tile.
// Epilogue: acc -> bf16 partials, thread-native layout, padded stride.
// ---------------------------------------------------------------------------
__global__ __launch_bounds__(512) void gemm_fused(const float* __restrict__ E,
                                                  ushort* __restrict__ part) {
    const int s    = blockIdx.x;
    const int tid  = threadIdx.x;
    const int lane = tid & 63;
    const int wid  = tid >> 6;
    const int wr   = wid >> 2;          // 0..1 -> 128-row band
    const int wc   = wid & 3;           // 0..3 -> 64-col band
    const int r15  = lane & 15;
    const int kgi  = lane >> 4;         // 0..3 -> 8-k slice within K=32

    __shared__ ushort Es[NROW][LR];     // 132 KB

    // ---------------- Phase A: stage block's K-chunk to LDS ----------------
    // wave covers rows [wid*32, wid*32+32); instr i (0..31):
    //   row = wid*32 + (i&3)*8 + (lane>>3), k-block = i>>2 (32 floats each)
    const int r8 = lane >> 3;
    const int g  = lane & 7;
    const size_t kb = (size_t)s * KB + (size_t)g * 4;

    auto LOADC = [&](float4* dst, int c) {
        #pragma unroll
        for (int u = 0; u < 8; ++u) {
            const int i    = c * 8 + u;
            const int row  = wid * 32 + (i & 3) * 8 + r8;
            const int kblk = i >> 2;
            dst[u] = *(const float4*)(E + (size_t)row * DIM + kb + kblk * 32);
        }
    };
    auto PROC = [&](const float4* src, int c) {
        #pragma unroll
        for (int u = 0; u < 8; ++u) {
            const int i    = c * 8 + u;
            const int row  = wid * 32 + (i & 3) * 8 + r8;
            const int kblk = i >> 2;
            uint2 wv;
            wv.x = pk2(src[u].x, src[u].y);
            wv.y = pk2(src[u].z, src[u].w);
            *(uint2*)&Es[row][kblk * 32 + g * 4] = wv;
        }
    };

    float4 va[8], vb[8];
    LOADC(va, 0);
    LOADC(vb, 1); PROC(va, 0);
    LOADC(va, 2); PROC(vb, 1);
    LOADC(vb, 3); PROC(va, 2);
    PROC(vb, 3);

    __syncthreads();    // the ONLY barrier

    // ---------------- Phase B: MFMA over 8 K=32 steps ----------------
    f32x4 acc[8][4];
    #pragma unroll
    for (int m = 0; m < 8; ++m)
        #pragma unroll
        for (int n = 0; n < 4; ++n) acc[m][n] = (f32x4){0.f, 0.f, 0.f, 0.f};

    #pragma unroll
    for (int kk = 0; kk < 8; ++kk) {
        const int ko = kk * 32 + kgi * 8;   // lane's 8-k slice (bf16 elems)
        short8 af[8], bfr[4];
        #pragma unroll
        for (int m = 0; m < 8; ++m)
            af[m] = *(const short8*)&Es[wr * 128 + m * 16 + r15][ko];
        #pragma unroll
        for (int n = 0; n < 4; ++n)
            bfr[n] = *(const short8*)&Es[wc * 64 + n * 16 + r15][ko];
        #pragma unroll
        for (int m = 0; m < 8; ++m)
            #pragma unroll
            for (int n = 0; n < 4; ++n)
                acc[m][n] = __builtin_amdgcn_mfma_f32_16x16x32_bf16(
                    af[m], bfr[n], acc[m][n], 0, 0, 0);
    }

    // epilogue: 128 accs -> bf16, contiguous per-thread (coalesced 16B stores)
    ushort* pp = part + (size_t)s * PSP + (size_t)tid * 128;
    #pragma unroll
    for (int m = 0; m < 8; ++m)
        #pragma unroll
        for (int n = 0; n < 4; n += 2) {
            uint4 q;
            q.x = pk2(acc[m][n][0],     acc[m][n][1]);
            q.y = pk2(acc[m][n][2],     acc[m][n][3]);
            q.z = pk2(acc[m][n + 1][0], acc[m][n + 1][1]);
            q.w = pk2(acc[m][n + 1][2], acc[m][n + 1][3]);
            *(uint4*)(pp + ((m << 2) | n) * 4) = q;
        }
}

// Fixed-order sum of 256 bf16 partials -> Gn (fp32, native layout). Padded
// partial stride kills power-of-2 set/channel aliasing of the column walk.
// Also zeroes the fixed-point accumulator for row_loss (stream-ordered).
__global__ __launch_bounds__(256) void reduce_k(const ushort* __restrict__ part,
                                                float* __restrict__ Gn,
                                                u64t* __restrict__ acc,
                                                u32t* __restrict__ cnt) {
    if (blockIdx.x == 0 && threadIdx.x == 0) { *acc = 0ull; *cnt = 0u; }

    const int b = blockIdx.x, t = threadIdx.x;
    const int l = t & 63, sg = t >> 6;
    const int n0 = b * 256 + l * 4;

    float a0 = 0.f, a1 = 0.f, a2 = 0.f, a3 = 0.f;
    for (int s = sg; s < 256; s += 4) {
        const ushort4 u = *(const ushort4*)&part[(size_t)s * PSP + n0];
        a0 += bf2f(u.x); a1 += bf2f(u.y); a2 += bf2f(u.z); a3 += bf2f(u.w);
    }
    __shared__ float sh[4][256];
    sh[sg][l * 4 + 0] = a0; sh[sg][l * 4 + 1] = a1;
    sh[sg][l * 4 + 2] = a2; sh[sg][l * 4 + 3] = a3;
    __syncthreads();
    Gn[b * 256 + t] = (sh[0][t] + sh[1][t]) + (sh[2][t] + sh[3][t]);
}

// ---------------------------------------------------------------------------
// Fused per-row softmax loss + deterministic final sum (fixed-point atomic,
// order-independent). PSD term provably 0 (AM-GM; clip at 0), omitted.
// ---------------------------------------------------------------------------
__global__ __launch_bounds__(256) void row_loss_k(const float* __restrict__ Gn,
                                                  const int* __restrict__ labels,
                                                  u64t* __restrict__ acc,
                                                  u32t* __restrict__ cnt,
                                                  float* __restrict__ out) {
    const int i = blockIdx.x;
    const int j = threadIdx.x;

    const float Gii = Gn[gpos(i, i)];
    const float Gjj = Gn[gpos(j, j)];
    const float Gij = Gn[gpos(i, j)];
    const float d2 = fmaxf(Gii + Gjj - 2.0f * Gij, 0.0f);
    const bool diag = (j == i);
    const float sc = diag ? -3.0e38f : -sqrtf(d2);

    __shared__ float red0[4], red1[4];

    float m = sc;
    #pragma unroll
    for (int off = 32; off; off >>= 1) m = fmaxf(m, __shfl_xor(m, off, 64));
    const int w = j >> 6;
    if ((j & 63) == 0) red0[w] = m;
    __syncthreads();
    m = fmaxf(fmaxf(red0[0], red0[1]), fmaxf(red0[2], red0[3]));

    const float p  = diag ? 0.0f : expf(sc - m);
    const float nm = (labels[j] == labels[i]) ? p : 0.0f;

    float zs = p, ns = nm;
    #pragma unroll
    for (int off = 32; off; off >>= 1) {
        zs += __shfl_xor(zs, off, 64);
        ns += __shfl_xor(ns, off, 64);
    }
    __syncthreads();
    if ((j & 63) == 0) { red0[w] = zs; red1[w] = ns; }
    __syncthreads();
    if (j == 0) {
        const float Z = red0[0] + red0[1] + red0[2] + red0[3];
        const float N = red1[0] + red1[1] + red1[2] + red1[3];
        const float rl = logf(Z) - logf(N);          // >= 0 (N subset of Z)
        const long long q = llrintf(rl * 1048576.0f);
        atomicAdd(acc, (u64t)q);
        __threadfence();
        const u32t c = atomicAdd(cnt, 1u);
        if (c == NROW - 1) {
            __threadfence();
            const u64t tot = atomicAdd(acc, 0ull);
            out[0] = (float)((double)(long long)tot * (1.0 / 1048576.0) * 0.005);
        }
    }
}

extern "C" void kernel_launch(void* const* d_in, const int* in_sizes, int n_in,
                              void* d_out, int out_size, void* d_ws, size_t ws_size,
                              hipStream_t stream) {
    const float* E      = (const float*)d_in[0];
    const int*   labels = (const int*)d_in[1];
    float*       out    = (float*)d_out;

    ushort* part = (ushort*)d_ws;                         // 256 * PSP ushorts
    float*  Gn   = (float*)((char*)d_ws + (size_t)256 * PSP * sizeof(ushort));
    u64t*   acc  = (u64t*)(Gn + NROW * NROW);
    u32t*   cnt  = (u32t*)(acc + 1);

    gemm_fused<<<256, 512, 0, stream>>>(E, part);
    reduce_k  <<<NROW, 256, 0, stream>>>(part, Gn, acc, cnt);
    row_loss_k<<<NROW, 256, 0, stream>>>(Gn, labels, acc, cnt, out);
}

// Round 7
// 45.396 us; speedup vs baseline: 1.3478x; 1.2868x over previous
//
#include <hip/hip_runtime.h>
#include <hip/hip_bf16.h>
#include <math.h>

#define NROW 256
#define DIM  65536
#define KB   256            // k-floats per block (P = 256 split-K blocks)
#define LR   264            // LDS row stride in bf16 elems (256 + 8 pad)
#define PSP  65600          // partial-buffer stride in ushorts (65536 + 64 pad)

typedef __attribute__((ext_vector_type(8))) short short8;
typedef __attribute__((ext_vector_type(4))) float f32x4;
typedef unsigned int       u32t;
typedef unsigned long long u64t;

__device__ __forceinline__ float bf2f(ushort h) {
    u32t u = ((u32t)h) << 16;
    return __builtin_bit_cast(float, u);
}
// packed fp32x2 -> bf16x2 (v_cvt_pk_bf16_f32, RNE)
__device__ __forceinline__ u32t pk2(float lo, float hi) {
    __hip_bfloat162 h = __float22bfloat162_rn(make_float2(lo, hi));
    u32t r; __builtin_memcpy(&r, &h, 4); return r;
}

// native-layout position of G[i][j] (matches gemm epilogue store order)
__device__ __forceinline__ int gpos(int i, int j) {
    const int wid  = ((i >> 7) << 2) | (j >> 6);
    const int lane = (((i >> 2) & 3) << 4) | (j & 15);
    const int m = (i >> 4) & 7, n = (j >> 4) & 3, jr = i & 3;
    return ((wid << 6) | lane) * 128 + (((m << 2) | n) << 2) + jr;
}

// ---------------------------------------------------------------------------
// Fused split-K MFMA GEMM, single-barrier, FULL-DEPTH phase A.
// Block s owns K-range [s*256, (s+1)*256).
// Phase A: issue ALL 32 float4 loads (512 B/thread in flight, 256 KB/CU),
//   then all 32 cvt_pk + ds_write_b64 (compiler interleaves decreasing
//   vmcnt waits). Wave streams each row's full 1 KB in 8 consecutive
//   instructions. LDS row stride 264 (banks rotate 4/row, balanced).
// ONE __syncthreads. Phase B: 8 pure-LDS MFMA k-steps. Epilogue: bf16
// partials, thread-native layout, coalesced 16 B/lane stores.
// ---------------------------------------------------------------------------
__global__ __launch_bounds__(512) void gemm_fused(const float* __restrict__ E,
                                                  ushort* __restrict__ part) {
    const int s    = blockIdx.x;
    const int tid  = threadIdx.x;
    const int lane = tid & 63;
    const int wid  = tid >> 6;
    const int r15  = lane & 15;
    const int kgi  = lane >> 4;         // 0..3 -> 8-k slice within K=32

    __shared__ ushort Es[NROW][LR];     // 132 KB

    // ---------------- Phase A ----------------
    const int r8   = lane >> 3;         // 0..7 row within 8-row group
    const int g    = lane & 7;          // 16B slot within 128B segment
    const int rowb = wid * 32 + r8;
    const float* __restrict__ gb = E + ((size_t)rowb << 16)
                                     + (size_t)s * KB + (size_t)g * 4;

    float4 v[32];
    #pragma unroll
    for (int c = 0; c < 4; ++c)         // 4 row-groups of 8 rows
        #pragma unroll
        for (int u = 0; u < 8; ++u)     // 8 k-chunks of 32 floats
            v[c * 8 + u] = *(const float4*)(gb + ((size_t)(c * 8) << 16) + u * 32);

    #pragma unroll
    for (int c = 0; c < 4; ++c)
        #pragma unroll
        for (int u = 0; u < 8; ++u) {
            const int row = rowb + c * 8;
            uint2 wv;
            wv.x = pk2(v[c * 8 + u].x, v[c * 8 + u].y);
            wv.y = pk2(v[c * 8 + u].z, v[c * 8 + u].w);
            *(uint2*)&Es[row][u * 32 + g * 4] = wv;
        }

    __syncthreads();    // the ONLY barrier

    // ---------------- Phase B: MFMA over 8 K=32 steps ----------------
    const int wr = wid >> 2;            // 0..1 -> 128-row band
    const int wc = wid & 3;             // 0..3 -> 64-col band

    f32x4 acc[8][4];
    #pragma unroll
    for (int m = 0; m < 8; ++m)
        #pragma unroll
        for (int n = 0; n < 4; ++n) acc[m][n] = (f32x4){0.f, 0.f, 0.f, 0.f};

    #pragma unroll
    for (int kk = 0; kk < 8; ++kk) {
        const int ko = kk * 32 + kgi * 8;   // lane's 8-k slice (bf16 elems)
        short8 af[8], bfr[4];
        #pragma unroll
        for (int m = 0; m < 8; ++m)
            af[m] = *(const short8*)&Es[wr * 128 + m * 16 + r15][ko];
        #pragma unroll
        for (int n = 0; n < 4; ++n)
            bfr[n] = *(const short8*)&Es[wc * 64 + n * 16 + r15][ko];
        #pragma unroll
        for (int m = 0; m < 8; ++m)
            #pragma unroll
            for (int n = 0; n < 4; ++n)
                acc[m][n] = __builtin_amdgcn_mfma_f32_16x16x32_bf16(
                    af[m], bfr[n], acc[m][n], 0, 0, 0);
    }

    // epilogue: 128 accs -> bf16, contiguous per-thread (coalesced 16B stores)
    ushort* pp = part + (size_t)s * PSP + (size_t)tid * 128;
    #pragma unroll
    for (int m = 0; m < 8; ++m)
        #pragma unroll
        for (int n = 0; n < 4; n += 2) {
            uint4 q;
            q.x = pk2(acc[m][n][0],     acc[m][n][1]);
            q.y = pk2(acc[m][n][2],     acc[m][n][3]);
            q.z = pk2(acc[m][n + 1][0], acc[m][n + 1][1]);
            q.w = pk2(acc[m][n + 1][2], acc[m][n + 1][3]);
            *(uint4*)(pp + ((m << 2) | n) * 4) = q;
        }
}

// ---------------------------------------------------------------------------
// Partial reduction, 512 blocks (2/CU): block (h, b) sums s-half h over a
// 512 B position window, 32 loads batched in flight. Writes Gh[h][pos].
// Deterministic fixed tree: u-ascending, then sg 0..3, then h0+h1 (row_loss).
// Also zeroes the fixed-point accumulator for row_loss (stream-ordered).
// ---------------------------------------------------------------------------
__global__ __launch_bounds__(256) void reduce_k(const ushort* __restrict__ part,
                                                float* __restrict__ Gh,
                                                u64t* __restrict__ acc,
                                                u32t* __restrict__ cnt) {
    if (blockIdx.x == 0 && threadIdx.x == 0) { *acc = 0ull; *cnt = 0u; }

    const int b = blockIdx.x & 255;     // position window
    const int h = blockIdx.x >> 8;      // s half
    const int t = threadIdx.x, l = t & 63, sg = t >> 6;
    const int n0 = b * 256 + l * 4;

    const ushort* base = part + (size_t)(h * 128 + sg) * PSP + n0;

    uint2 r[32];
    #pragma unroll
    for (int u = 0; u < 32; ++u)
        r[u] = *(const uint2*)(base + (size_t)(4 * u) * PSP);

    float a0 = 0.f, a1 = 0.f, a2 = 0.f, a3 = 0.f;
    #pragma unroll
    for (int u = 0; u < 32; ++u) {
        a0 += bf2f((ushort)(r[u].x & 0xffffu));
        a1 += bf2f((ushort)(r[u].x >> 16));
        a2 += bf2f((ushort)(r[u].y & 0xffffu));
        a3 += bf2f((ushort)(r[u].y >> 16));
    }
    __shared__ float sh[4][256];
    sh[sg][l * 4 + 0] = a0; sh[sg][l * 4 + 1] = a1;
    sh[sg][l * 4 + 2] = a2; sh[sg][l * 4 + 3] = a3;
    __syncthreads();
    Gh[(size_t)h * 65536 + b * 256 + t] =
        (sh[0][t] + sh[1][t]) + (sh[2][t] + sh[3][t]);
}

// ---------------------------------------------------------------------------
// Fused per-row softmax loss + deterministic final sum (fixed-point atomic,
// order-independent). PSD term provably 0 (AM-GM; clip at 0), omitted.
// ---------------------------------------------------------------------------
__global__ __launch_bounds__(256) void row_loss_k(const float* __restrict__ Gh,
                                                  const int* __restrict__ labels,
                                                  u64t* __restrict__ acc,
                                                  u32t* __restrict__ cnt,
                                                  float* __restrict__ out) {
    const int i = blockIdx.x;
    const int j = threadIdx.x;

    const int pii = gpos(i, i), pjj = gpos(j, j), pij = gpos(i, j);
    const float Gii = Gh[pii] + Gh[65536 + pii];
    const float Gjj = Gh[pjj] + Gh[65536 + pjj];
    const float Gij = Gh[pij] + Gh[65536 + pij];
    const float d2 = fmaxf(Gii + Gjj - 2.0f * Gij, 0.0f);
    const bool diag = (j == i);
    const float sc = diag ? -3.0e38f : -sqrtf(d2);

    __shared__ float red0[4], red1[4];

    float m = sc;
    #pragma unroll
    for (int off = 32; off; off >>= 1) m = fmaxf(m, __shfl_xor(m, off, 64));
    const int w = j >> 6;
    if ((j & 63) == 0) red0[w] = m;
    __syncthreads();
    m = fmaxf(fmaxf(red0[0], red0[1]), fmaxf(red0[2], red0[3]));

    const float p  = diag ? 0.0f : expf(sc - m);
    const float nm = (labels[j] == labels[i]) ? p : 0.0f;

    float zs = p, ns = nm;
    #pragma unroll
    for (int off = 32; off; off >>= 1) {
        zs += __shfl_xor(zs, off, 64);
        ns += __shfl_xor(ns, off, 64);
    }
    __syncthreads();
    if ((j & 63) == 0) { red0[w] = zs; red1[w] = ns; }
    __syncthreads();
    if (j == 0) {
        const float Z = red0[0] + red0[1] + red0[2] + red0[3];
        const float N = red1[0] + red1[1] + red1[2] + red1[3];
        const float rl = logf(Z) - logf(N);          // >= 0 (N subset of Z)
        const long long q = llrintf(rl * 1048576.0f);
        atomicAdd(acc, (u64t)q);
        __threadfence();
        const u32t c = atomicAdd(cnt, 1u);
        if (c == NROW - 1) {
            __threadfence();
            const u64t tot = atomicAdd(acc, 0ull);
            out[0] = (float)((double)(long long)tot * (1.0 / 1048576.0) * 0.005);
        }
    }
}

extern "C" void kernel_launch(void* const* d_in, const int* in_sizes, int n_in,
                              void* d_out, int out_size, void* d_ws, size_t ws_size,
                              hipStream_t stream) {
    const float* E      = (const float*)d_in[0];
    const int*   labels = (const int*)d_in[1];
    float*       out    = (float*)d_out;

    ushort* part = (ushort*)d_ws;                         // 256 * PSP ushorts
    float*  Gh   = (float*)((char*)d_ws + (size_t)256 * PSP * sizeof(ushort));
    u64t*   acc  = (u64t*)(Gh + 2 * NROW * NROW);
    u32t*   cnt  = (u32t*)(acc + 1);

    gemm_fused<<<256, 512, 0, stream>>>(E, part);
    reduce_k  <<<512, 256, 0, stream>>>(part, Gh, acc, cnt);
    row_loss_k<<<NROW, 256, 0, stream>>>(Gh, labels, acc, cnt, out);
}